// Round 13
// baseline (661.599 us; speedup 1.0000x reference)
//
#include <hip/hip_runtime.h>
#include <math.h>

#define BB 8
#define CC 256
#define NN 4096

typedef float f4 __attribute__((ext_vector_type(4)));
typedef short bh8 __attribute__((ext_vector_type(8)));

__device__ __forceinline__ unsigned short f2bf(float f) {
    unsigned u = __builtin_bit_cast(unsigned, f);
    u += 0x7fff + ((u >> 16) & 1);
    return (unsigned short)(u >> 16);
}
__device__ __forceinline__ unsigned packbf(float a, float b) {
    return (unsigned)f2bf(a) | ((unsigned)f2bf(b) << 16);
}

// v_exp_f32 is natively 2^x — scores are pre-scaled by log2(e) in prep_w
__device__ __forceinline__ float exp2_fast(float x) {
    float r;
    asm("v_exp_f32 %0, %1" : "=v"(r) : "v"(x));
    return r;
}

// ---------------------------------------------------------------------------
// Kernel 0: concatenate weights into WcatT[c][320] + bcat[320] (fp32).
// q rows (o<32) pre-scaled by log2(e) so softmax uses raw v_exp_f32 (2^x).
// ---------------------------------------------------------------------------
__global__ void prep_w_kernel(const float* __restrict__ Wq, const float* __restrict__ bq,
                              const float* __restrict__ Wk, const float* __restrict__ bk,
                              const float* __restrict__ Wv, const float* __restrict__ bv,
                              float* __restrict__ WcatT, float* __restrict__ bcat) {
    const float L2E = 1.4426950408889634f;
    int idx = blockIdx.x * 256 + threadIdx.x;
    if (idx < 320) {
        bcat[idx] = (idx < 32) ? bq[idx] * L2E : (idx < 64 ? bk[idx - 32] : bv[idx - 64]);
    }
    if (idx < 320 * 256) {
        int o = idx >> 8;
        int c = idx & 255;
        float v = (o < 32) ? Wq[o * 256 + c] * L2E
                           : (o < 64 ? Wk[(o - 32) * 256 + c] : Wv[(o - 64) * 256 + c]);
        WcatT[c * 320 + o] = v;
    }
}

// ---------------------------------------------------------------------------
// Kernel 1: QKV projection (fp32 math), bf16 outputs. (R12 version, proven)
// V written with sigma key-permutation per 32-column block so the attention
// PV B-fragment equals each lane's own score registers.
// ---------------------------------------------------------------------------
__global__ __launch_bounds__(256, 2) void qkv_kernel(
    const float* __restrict__ x, const float* __restrict__ WcatT,
    const float* __restrict__ bcat,
    unsigned short* __restrict__ q64, unsigned short* __restrict__ k64,
    unsigned short* __restrict__ vC) {
    __shared__ float xs[256 * 64];
    __shared__ unsigned short qkl[64 * 128];
    unsigned short* vsl = (unsigned short*)xs;  // [256][66] u16 overlay

    int blk = blockIdx.x;
    int b = blk >> 6;
    int i0 = (blk & 63) << 6;
    int t = threadIdx.x;

    const float* xb = x + ((size_t)b << 20);
    for (int idx = t; idx < 256 * 64; idx += 256) {
        int c = idx >> 6, ii = idx & 63;
        xs[idx] = xb[((size_t)c << 12) + i0 + ii];
    }
    __syncthreads();

    int to = t & 63;
    int tp = t >> 6;  // wave-uniform

    float acc[80];
#pragma unroll
    for (int uo = 0; uo < 5; ++uo) {
        float bias = bcat[to + 64 * uo];
#pragma unroll
        for (int pi = 0; pi < 16; ++pi) acc[uo * 16 + pi] = bias;
    }

    for (int c = 0; c < 256; ++c) {
        const float* wc = WcatT + c * 320 + to;
        float w0 = wc[0];
        float w1 = wc[64];
        float w2 = wc[128];
        float w3 = wc[192];
        float w4 = wc[256];
        const float4* xr = (const float4*)(xs + c * 64 + 16 * tp);
#pragma unroll
        for (int q = 0; q < 4; ++q) {
            float4 xv = xr[q];  // broadcast (wave-uniform address)
#pragma unroll
            for (int e = 0; e < 4; ++e) {
                int pi = 4 * q + e;
                float xe = (e == 0) ? xv.x : (e == 1) ? xv.y : (e == 2) ? xv.z : xv.w;
                acc[0 * 16 + pi] += w0 * xe;
                acc[1 * 16 + pi] += w1 * xe;
                acc[2 * 16 + pi] += w2 * xe;
                acc[3 * 16 + pi] += w3 * xe;
                acc[4 * 16 + pi] += w4 * xe;
            }
        }
    }
    __syncthreads();

#pragma unroll
    for (int pi = 0; pi < 16; ++pi) {
        int ii = 16 * tp + pi;
        float v = acc[pi];  // uo == 0
        unsigned short hi = f2bf(v);
        float vhi = __builtin_bit_cast(float, ((unsigned)hi) << 16);
        unsigned short lo = f2bf(v - vhi);
        if (to < 32) {
            qkl[ii * 128 + to] = hi;
            qkl[ii * 128 + 32 + to] = lo;
        } else {
            qkl[ii * 128 + 32 + to] = hi;
            qkl[ii * 128 + 64 + to] = lo;
        }
    }
#pragma unroll
    for (int uo = 1; uo < 5; ++uo) {
#pragma unroll
        for (int pi = 0; pi < 16; ++pi) {
            int c = to + 64 * (uo - 1);
            int ii = 16 * tp + pi;
            vsl[c * 66 + ii] = f2bf(acc[uo * 16 + pi]);
        }
    }
    __syncthreads();

    const unsigned* qk32 = (const unsigned*)qkl;
    unsigned* qb = (unsigned*)(q64 + ((size_t)(b * NN + i0)) * 64);
    unsigned* kb = (unsigned*)(k64 + ((size_t)(b * NN + i0)) * 64);
    for (int idx = t; idx < 64 * 32; idx += 256) {
        int row = idx >> 5, dw = idx & 31;
        qb[row * 32 + dw] = qk32[row * 64 + dw];
        kb[row * 32 + dw] = qk32[row * 64 + 32 + dw];
    }
    // V copy-out with sigma^-1 column remap (pairs i,i+1 stay adjacent)
    for (int idx = t; idx < 256 * 32; idx += 256) {
        int c = idx >> 5, dw = idx & 31;
        unsigned val = *(const unsigned*)(vsl + c * 66 + 2 * dw);
        int i = 2 * dw;
        int p = 32 * (i >> 5) + 8 * ((i >> 2) & 3) + 4 * ((i >> 4) & 1) + (i & 3);
        *(unsigned*)(vC + ((size_t)(b * CC + c)) * NN + i0 + p) = val;
    }
}

// ---------------------------------------------------------------------------
// Kernel 2: MFMA flash attention + residual. BARRIER-FREE, no LDS.
// Grid 512 (8 b x 64 q-tiles), 4 independent waves x 16 queries.
// V per batch = 2MB, XCD-affine L2-resident (b = blk&7 == XCD id on the
// round-robin dispatch); V fragments read DIRECTLY from global: per lane a
// contiguous 16B at vb + c*NN + j0 + 32h + 8g (li-group covers whole 64B
// lines; L1 dedups the 8-wave reuse). Zero __syncthreads in the kernel.
// PV pipelined in 4 groups of 8 fragments (short 32-VGPR live ranges).
// QK: S^T = mfma_16x16x32(A=K,B=Q), 3-product split-bf16, exp2 domain.
// PV B-frag = lane's OWN scores (sigma-permuted V). Vote-only defer-max.
// ---------------------------------------------------------------------------
__global__ __launch_bounds__(256, 1) void attn_kernel(
    const unsigned short* __restrict__ q64, const unsigned short* __restrict__ k64,
    const unsigned short* __restrict__ vC, const float* __restrict__ x,
    const float* __restrict__ gamma, float* __restrict__ out) {
    int t = threadIdx.x;
    int lane = t & 63;
    int w = t >> 6;
    int g = lane >> 4;
    int li = lane & 15;
    int blk = blockIdx.x;
    int b = blk & 7;            // XCD-affine batch mapping
    int i0 = (blk >> 3) << 6;   // 64-query tile
    int qb = i0 + 16 * w;       // wave's query base (16 queries)

    const unsigned short* vb = vC + ((size_t)b * CC) * NN;
    const unsigned short* kb = k64 + ((size_t)b * NN) * 64;

    // Q fragments (resident): [hi/lo]
    bh8 qf[2];
#pragma unroll
    for (int s = 0; s < 2; ++s)
        qf[s] = *(const bh8*)(q64 + ((size_t)(b * NN + qb + li)) * 64 + s * 32 + 8 * g);

    // per-lane base pointers (single pointer + unrolled-constant offsets)
    const unsigned short* kbase = kb + (size_t)li * 64 + 8 * g;
    const unsigned short* vbase = vb + (size_t)li * NN + 8 * g;

    f4 acc[16];
#pragma unroll
    for (int ct = 0; ct < 16; ++ct) acc[ct] = (f4){0.f, 0.f, 0.f, 0.f};
    float m = -INFINITY, l = 0.f;  // l is a per-lane PARTIAL (reduced at end)

    auto loadK = [&](bh8 (&kf)[4][2], int j0) {
        size_t joff = (size_t)j0 * 64;
#pragma unroll
        for (int jt = 0; jt < 4; ++jt)
#pragma unroll
            for (int s = 0; s < 2; ++s)
                kf[jt][s] = *(const bh8*)(kbase + joff + jt * (16 * 64) + s * 32);
    };
    // V fragment: channel 16ct+li, sigma-columns j0+32h+8g..+7 (16B)
    auto vload = [&](int ct, int h, int j0) -> bh8 {
        return *(const bh8*)(vbase + (size_t)ct * (16 * NN) + j0 + 32 * h);
    };
    // QK^T (swapped, 3-product bf16 split => ~fp32 scores, log2e-scaled)
    auto qkComp = [&](f4 (&sOut)[4], bh8 (&kc)[4][2]) {
#pragma unroll
        for (int jt = 0; jt < 4; ++jt) {
            f4 a = {0.f, 0.f, 0.f, 0.f};
            a = __builtin_amdgcn_mfma_f32_16x16x32_bf16(kc[jt][0], qf[0], a, 0, 0, 0);
            a = __builtin_amdgcn_mfma_f32_16x16x32_bf16(kc[jt][1], qf[0], a, 0, 0, 0);
            a = __builtin_amdgcn_mfma_f32_16x16x32_bf16(kc[jt][0], qf[1], a, 0, 0, 0);
            sOut[jt] = a;
        }
    };

    bh8 kf0[4][2], kf1[4][2];
    f4 sA[4], sB[4];

    // prologue: K[0]/K[1] in regs, S[0] computed (no staging, no sync)
    loadK(kf0, 0);
    loadK(kf1, 64);
    qkComp(sA, kf0);

    auto step = [&](int tt, bh8 (&kNext)[4][2], bh8 (&kLoad)[4][2],
                    f4 (&sCur)[4], f4 (&sNxt)[4]) {
        int j0 = tt << 6;
        if (tt < 62) loadK(kLoad, (tt + 2) << 6);

        // ---- QK for tile tt+1 (independent of sCur) ----
        if (tt < 63) qkComp(sNxt, kNext);

        // ---- G0 V issue (h=0, ct 0..7): L2 latency hides under softmax ----
        bh8 va[8], vb2[8];
#pragma unroll
        for (int ct = 0; ct < 8; ++ct) va[ct] = vload(ct, 0, j0);

        // ---- softmax: vote-only defer-max, reductions only in rare branch --
        float mx = sCur[0][0];
#pragma unroll
        for (int jt = 0; jt < 4; ++jt)
#pragma unroll
            for (int e = 0; e < 4; ++e) mx = fmaxf(mx, sCur[jt][e]);
        if (!__all(mx <= m + 11.541561f)) {
            mx = fmaxf(mx, __shfl_xor(mx, 16));
            mx = fmaxf(mx, __shfl_xor(mx, 32));
            float mnew = fmaxf(m, mx);
            float sc = exp2_fast(m - mnew);
            l *= sc;
#pragma unroll
            for (int ct = 0; ct < 16; ++ct)
#pragma unroll
                for (int e = 0; e < 4; ++e) acc[ct][e] *= sc;
            m = mnew;
        }
        float sum = 0.f;
#pragma unroll
        for (int jt = 0; jt < 4; ++jt)
#pragma unroll
            for (int e = 0; e < 4; ++e) {
                float p = exp2_fast(sCur[jt][e] - m);
                sCur[jt][e] = p;
                sum += p;
            }
        l += sum;  // per-lane partial; no shfl here

        // ---- P fragments = own scores packed (sigma-permuted V) ----
        union { unsigned u[4]; bh8 v; } pf0, pf1;
        pf0.u[0] = packbf(sCur[0][0], sCur[0][1]);
        pf0.u[1] = packbf(sCur[0][2], sCur[0][3]);
        pf0.u[2] = packbf(sCur[1][0], sCur[1][1]);
        pf0.u[3] = packbf(sCur[1][2], sCur[1][3]);
        pf1.u[0] = packbf(sCur[2][0], sCur[2][1]);
        pf1.u[1] = packbf(sCur[2][2], sCur[2][3]);
        pf1.u[2] = packbf(sCur[3][0], sCur[3][1]);
        pf1.u[3] = packbf(sCur[3][2], sCur[3][3]);
        bh8 pb0 = pf0.v, pb1 = pf1.v;

        // ---- PV in 4 groups of 8; each group's loads issue one group early
#pragma unroll
        for (int ct = 0; ct < 8; ++ct) vb2[ct] = vload(ct + 8, 0, j0);  // G1
        __builtin_amdgcn_s_setprio(1);
#pragma unroll
        for (int ct = 0; ct < 8; ++ct)
            acc[ct] = __builtin_amdgcn_mfma_f32_16x16x32_bf16(va[ct], pb0, acc[ct], 0, 0, 0);
        __builtin_amdgcn_s_setprio(0);
#pragma unroll
        for (int ct = 0; ct < 8; ++ct) va[ct] = vload(ct, 1, j0);       // G2
        __builtin_amdgcn_s_setprio(1);
#pragma unroll
        for (int ct = 0; ct < 8; ++ct)
            acc[ct + 8] = __builtin_amdgcn_mfma_f32_16x16x32_bf16(vb2[ct], pb0, acc[ct + 8], 0, 0, 0);
        __builtin_amdgcn_s_setprio(0);
#pragma unroll
        for (int ct = 0; ct < 8; ++ct) vb2[ct] = vload(ct + 8, 1, j0);  // G3
        __builtin_amdgcn_s_setprio(1);
#pragma unroll
        for (int ct = 0; ct < 8; ++ct)
            acc[ct] = __builtin_amdgcn_mfma_f32_16x16x32_bf16(va[ct], pb1, acc[ct], 0, 0, 0);
#pragma unroll
        for (int ct = 0; ct < 8; ++ct)
            acc[ct + 8] = __builtin_amdgcn_mfma_f32_16x16x32_bf16(vb2[ct], pb1, acc[ct + 8], 0, 0, 0);
        __builtin_amdgcn_s_setprio(0);
        // NO barrier — waves are fully independent
    };

    for (int tt = 0; tt < 64; tt += 2) {
        step(tt, kf1, kf0, sA, sB);
        step(tt + 1, kf0, kf1, sB, sA);
    }

    // ---- reduce l across the 4-lane query group (deferred) ----
    l += __shfl_xor(l, 16);
    l += __shfl_xor(l, 32);

    // ---- epilogue: out = gamma*(acc/l) + x ----
    float gm = gamma[0];
    float rl = 1.f / l;
    const float* xb = x + ((size_t)b * CC) * NN;
    float* ob = out + ((size_t)b * CC) * NN;
    int i = qb + li;
#pragma unroll
    for (int ct = 0; ct < 16; ++ct)
#pragma unroll
        for (int e = 0; e < 4; ++e) {
            int c = 16 * ct + 4 * g + e;
            size_t idx = (size_t)c * NN + i;
            ob[idx] = gm * (acc[ct][e] * rl) + xb[idx];
        }
}

// ---------------------------------------------------------------------------
extern "C" void kernel_launch(void* const* d_in, const int* in_sizes, int n_in,
                              void* d_out, int out_size, void* d_ws, size_t ws_size,
                              hipStream_t stream) {
    const float* x = (const float*)d_in[0];
    const float* Wq = (const float*)d_in[1];
    const float* bq = (const float*)d_in[2];
    const float* Wk = (const float*)d_in[3];
    const float* bk = (const float*)d_in[4];
    const float* Wv = (const float*)d_in[5];
    const float* bv = (const float*)d_in[6];
    const float* gamma = (const float*)d_in[7];
    float* out = (float*)d_out;

    // workspace layout (bytes):
    // q64 @0 (4MB) | k64 @4MB (4MB) | vC @8MB (16MB) | WcatT @24MB | bcat
    unsigned short* ws16 = (unsigned short*)d_ws;
    unsigned short* q64w = ws16;
    unsigned short* k64w = ws16 + 2097152;
    unsigned short* vCw = ws16 + 4194304;
    float* WcatT = (float*)((char*)d_ws + 25165824);
    float* bcat = WcatT + 81920;

    prep_w_kernel<<<320, 256, 0, stream>>>(Wq, bq, Wk, bk, Wv, bv, WcatT, bcat);
    qkv_kernel<<<BB * (NN / 64), 256, 0, stream>>>(x, WcatT, bcat, q64w, k64w, vCw);
    attn_kernel<<<512, 256, 0, stream>>>(q64w, k64w, vCw, x, gamma, out);
}

// Round 14
// 205.460 us; speedup vs baseline: 3.2201x; 3.2201x over previous
//
#include <hip/hip_runtime.h>
#include <math.h>

#define BB 8
#define CC 256
#define NN 4096

typedef float f4 __attribute__((ext_vector_type(4)));
typedef short bh8 __attribute__((ext_vector_type(8)));

__device__ __forceinline__ unsigned short f2bf(float f) {
    unsigned u = __builtin_bit_cast(unsigned, f);
    u += 0x7fff + ((u >> 16) & 1);
    return (unsigned short)(u >> 16);
}
__device__ __forceinline__ unsigned packbf(float a, float b) {
    return (unsigned)f2bf(a) | ((unsigned)f2bf(b) << 16);
}

// v_exp_f32 is natively 2^x — scores are pre-scaled by log2(e) in prep_w
__device__ __forceinline__ float exp2_fast(float x) {
    float r;
    asm("v_exp_f32 %0, %1" : "=v"(r) : "v"(x));
    return r;
}

// ---------------------------------------------------------------------------
// Kernel 0: weights -> Whi/Wlo[320][256] (bf16 hi/lo split, row-major over c)
// + bcat[320] fp32. q rows (o<32) pre-scaled by log2(e).
// ---------------------------------------------------------------------------
__global__ void prep_w_kernel(const float* __restrict__ Wq, const float* __restrict__ bq,
                              const float* __restrict__ Wk, const float* __restrict__ bk,
                              const float* __restrict__ Wv, const float* __restrict__ bv,
                              unsigned short* __restrict__ Whi, unsigned short* __restrict__ Wlo,
                              float* __restrict__ bcat) {
    const float L2E = 1.4426950408889634f;
    int idx = blockIdx.x * 256 + threadIdx.x;
    if (idx < 320) {
        bcat[idx] = (idx < 32) ? bq[idx] * L2E : (idx < 64 ? bk[idx - 32] : bv[idx - 64]);
    }
    if (idx < 320 * 256) {
        int o = idx >> 8;
        int c = idx & 255;
        float v = (o < 32) ? Wq[o * 256 + c] * L2E
                           : (o < 64 ? Wk[(o - 32) * 256 + c] : Wv[(o - 64) * 256 + c]);
        unsigned short hi = f2bf(v);
        float vhi = __builtin_bit_cast(float, ((unsigned)hi) << 16);
        Whi[idx] = hi;
        Wlo[idx] = f2bf(v - vhi);
    }
}

// ---------------------------------------------------------------------------
// Kernel 1: QKV projection via MFMA.
// Block = 256 threads (4 waves), one (b, 64-position tile). Grid 512.
// Phase 1: stage x tile TRANSPOSED into LDS as bf16 hi/lo ([64][264] pad:
//   read bank-groups (li+g)%8 tile all 32 banks -> conflict-free b128 reads).
// Phase 2: wave w computes o-tiles {w, w+4, w+8, w+12, w+16} (one q/k tile +
//   four v tiles each): A = W rows (kf-pattern), B = x^T rows (qf-pattern).
//   q/k: 3-product split (fp32-grade); v: 2-product (W exact).
// Phase 3 (LDS overlay): staging writes identical in layout to the old
//   kernel; Phase 4: copy-out UNCHANGED (incl. sigma V column remap).
// ---------------------------------------------------------------------------
__global__ __launch_bounds__(256, 2) void qkv_kernel(
    const float* __restrict__ x, const unsigned short* __restrict__ Whi,
    const unsigned short* __restrict__ Wlo, const float* __restrict__ bcat,
    unsigned short* __restrict__ q64, unsigned short* __restrict__ k64,
    unsigned short* __restrict__ vC) {
    __shared__ __align__(16) char smem[67584];
    unsigned short* xsTh = (unsigned short*)smem;            // [64][264]
    unsigned short* xsTl = (unsigned short*)(smem + 33792);  // [64][264]
    unsigned short* qkl = (unsigned short*)smem;             // [64][128] overlay
    unsigned short* vsl = (unsigned short*)(smem + 16384);   // [256][66] overlay

    int blk = blockIdx.x;
    int b = blk >> 6;
    int i0 = (blk & 63) << 6;
    int t = threadIdx.x;
    const float* xb = x + ((size_t)b << 20);

    // ---- phase 1: transposed staging + hi/lo split ----
    for (int idx = t; idx < 256 * 64; idx += 256) {
        int c = idx >> 6, ii = idx & 63;
        float v = xb[((size_t)c << 12) + i0 + ii];
        unsigned short hi = f2bf(v);
        float vhi = __builtin_bit_cast(float, ((unsigned)hi) << 16);
        xsTh[ii * 264 + c] = hi;
        xsTl[ii * 264 + c] = f2bf(v - vhi);
    }
    __syncthreads();

    int lane = t & 63;
    int w = t >> 6;
    int g = lane >> 4;
    int li = lane & 15;

    // ---- phase 2: MFMA compute ----
    f4 acc[5][4];
#pragma unroll
    for (int tt = 0; tt < 5; ++tt)
#pragma unroll
        for (int it = 0; it < 4; ++it) acc[tt][it] = (f4){0.f, 0.f, 0.f, 0.f};

#pragma unroll
    for (int tt = 0; tt < 5; ++tt) {
        int ot = w + 4 * tt;           // wave-uniform
        bool qk = (ot < 4);            // wave-uniform branch
        const unsigned short* wrh = Whi + (size_t)(16 * ot + li) * 256 + 8 * g;
        const unsigned short* wrl = Wlo + (size_t)(16 * ot + li) * 256 + 8 * g;
        bh8 ah[8], al[8];
#pragma unroll
        for (int ck = 0; ck < 8; ++ck) {
            ah[ck] = *(const bh8*)(wrh + 32 * ck);
            al[ck] = *(const bh8*)(wrl + 32 * ck);
        }
#pragma unroll
        for (int it = 0; it < 4; ++it) {
            const unsigned short* xrh = xsTh + (16 * it + li) * 264 + 8 * g;
            const unsigned short* xrl = xsTl + (16 * it + li) * 264 + 8 * g;
            f4 a = acc[tt][it];
            if (qk) {
#pragma unroll
                for (int ck = 0; ck < 8; ++ck) {
                    bh8 xh = *(const bh8*)(xrh + 32 * ck);
                    bh8 xl = *(const bh8*)(xrl + 32 * ck);
                    a = __builtin_amdgcn_mfma_f32_16x16x32_bf16(ah[ck], xh, a, 0, 0, 0);
                    a = __builtin_amdgcn_mfma_f32_16x16x32_bf16(al[ck], xh, a, 0, 0, 0);
                    a = __builtin_amdgcn_mfma_f32_16x16x32_bf16(ah[ck], xl, a, 0, 0, 0);
                }
            } else {
#pragma unroll
                for (int ck = 0; ck < 8; ++ck) {
                    bh8 xh = *(const bh8*)(xrh + 32 * ck);
                    a = __builtin_amdgcn_mfma_f32_16x16x32_bf16(ah[ck], xh, a, 0, 0, 0);
                    a = __builtin_amdgcn_mfma_f32_16x16x32_bf16(al[ck], xh, a, 0, 0, 0);
                }
            }
            acc[tt][it] = a;
        }
    }
    __syncthreads();  // all xsT reads done; safe to overlay qkl/vsl

    // ---- phase 3: staging writes (+bias), same layout as old kernel ----
#pragma unroll
    for (int tt = 0; tt < 5; ++tt) {
        int ot = w + 4 * tt;
        float bias[4];
#pragma unroll
        for (int e = 0; e < 4; ++e) bias[e] = bcat[16 * ot + 4 * g + e];
#pragma unroll
        for (int it = 0; it < 4; ++it) {
            int ii = 16 * it + li;
#pragma unroll
            for (int e = 0; e < 4; ++e) {
                int o = 16 * ot + 4 * g + e;
                float v = acc[tt][it][e] + bias[e];
                if (o < 64) {
                    unsigned short hi = f2bf(v);
                    float vhi = __builtin_bit_cast(float, ((unsigned)hi) << 16);
                    unsigned short lo = f2bf(v - vhi);
                    if (o < 32) {
                        qkl[ii * 128 + o] = hi;
                        qkl[ii * 128 + 32 + o] = lo;
                    } else {
                        qkl[ii * 128 + 32 + o] = hi;
                        qkl[ii * 128 + 64 + o] = lo;
                    }
                } else {
                    vsl[(o - 64) * 66 + ii] = f2bf(v);
                }
            }
        }
    }
    __syncthreads();

    // ---- phase 4: copy-out (unchanged, incl. sigma V column remap) ----
    const unsigned* qk32 = (const unsigned*)qkl;
    unsigned* qb = (unsigned*)(q64 + ((size_t)(b * NN + i0)) * 64);
    unsigned* kb = (unsigned*)(k64 + ((size_t)(b * NN + i0)) * 64);
    for (int idx = t; idx < 64 * 32; idx += 256) {
        int row = idx >> 5, dw = idx & 31;
        qb[row * 32 + dw] = qk32[row * 64 + dw];
        kb[row * 32 + dw] = qk32[row * 64 + 32 + dw];
    }
    for (int idx = t; idx < 256 * 32; idx += 256) {
        int c = idx >> 5, dw = idx & 31;
        unsigned val = *(const unsigned*)(vsl + c * 66 + 2 * dw);
        int i = 2 * dw;
        int p = 32 * (i >> 5) + 8 * ((i >> 2) & 3) + 4 * ((i >> 4) & 1) + (i & 3);
        *(unsigned*)(vC + ((size_t)(b * CC + c)) * NN + i0 + p) = val;
    }
}

// ---------------------------------------------------------------------------
// Kernel 2: MFMA flash attention + residual. (R12 verbatim — proven 182 µs,
// zero bank conflicts, zero steady-state cross-lane.)
// ---------------------------------------------------------------------------
__global__ __launch_bounds__(256, 2) void attn_kernel(
    const unsigned short* __restrict__ q64, const unsigned short* __restrict__ k64,
    const unsigned short* __restrict__ vC, const float* __restrict__ x,
    const float* __restrict__ gamma, float* __restrict__ out) {
    __shared__ unsigned short vs[2][256 * 64];  // 64KB double-buffered V

    int t = threadIdx.x;
    int lane = t & 63;
    int w = t >> 6;
    int g = lane >> 4;
    int li = lane & 15;
    int blk = blockIdx.x;
    int b = blk & 7;            // XCD-affine batch mapping
    int i0 = (blk >> 3) << 6;   // 64-query tile
    int qb = i0 + 16 * w;       // wave's query base (16 queries)

    const unsigned short* vb = vC + ((size_t)b * CC) * NN;
    const unsigned short* kb = k64 + ((size_t)b * NN) * 64;

    bh8 qf[2];
#pragma unroll
    for (int s = 0; s < 2; ++s)
        qf[s] = *(const bh8*)(q64 + ((size_t)(b * NN + qb + li)) * 64 + s * 32 + 8 * g);

    const unsigned short* vsrcb[8];
#pragma unroll
    for (int s = 0; s < 8; ++s) {
        int c = 64 * w + 8 * s + (lane >> 3);
        int slot = (lane & 7) ^ (c & 7);
        vsrcb[s] = vb + (size_t)c * NN + slot * 8;
    }
    const unsigned short* ksrcb[8];
#pragma unroll
    for (int jt = 0; jt < 4; ++jt)
#pragma unroll
        for (int s = 0; s < 2; ++s)
            ksrcb[jt * 2 + s] = kb + (size_t)(16 * jt + li) * 64 + s * 32 + 8 * g;

    f4 acc[16];
#pragma unroll
    for (int ct = 0; ct < 16; ++ct) acc[ct] = (f4){0.f, 0.f, 0.f, 0.f};
    float m = -INFINITY, l = 0.f;

    auto stageV = [&](int buf, int j0) {
#pragma unroll
        for (int s = 0; s < 8; ++s) {
            __builtin_amdgcn_global_load_lds(
                (const __attribute__((address_space(1))) unsigned int*)(vsrcb[s] + j0),
                (__attribute__((address_space(3))) unsigned int*)(&vs[buf][(64 * w + 8 * s) * 64]),
                16, 0, 0);
        }
    };
    auto loadK = [&](bh8 (&kf)[4][2], int j0) {
        size_t joff = (size_t)j0 * 64;
#pragma unroll
        for (int jt = 0; jt < 4; ++jt)
#pragma unroll
            for (int s = 0; s < 2; ++s)
                kf[jt][s] = *(const bh8*)(ksrcb[jt * 2 + s] + joff);
    };
    auto qkComp = [&](f4 (&sOut)[4], bh8 (&kc)[4][2]) {
#pragma unroll
        for (int jt = 0; jt < 4; ++jt) {
            f4 a = {0.f, 0.f, 0.f, 0.f};
            a = __builtin_amdgcn_mfma_f32_16x16x32_bf16(kc[jt][0], qf[0], a, 0, 0, 0);
            a = __builtin_amdgcn_mfma_f32_16x16x32_bf16(kc[jt][1], qf[0], a, 0, 0, 0);
            a = __builtin_amdgcn_mfma_f32_16x16x32_bf16(kc[jt][0], qf[1], a, 0, 0, 0);
            sOut[jt] = a;
        }
    };

    bh8 kf0[4][2], kf1[4][2];
    f4 sA[4], sB[4];

    stageV(0, 0);
    loadK(kf0, 0);
    loadK(kf1, 64);
    qkComp(sA, kf0);
    __syncthreads();

    auto step = [&](int tt, bh8 (&kNext)[4][2], bh8 (&kLoad)[4][2],
                    f4 (&sCur)[4], f4 (&sNxt)[4], int buf) {
        if (tt < 63) stageV(buf ^ 1, (tt + 1) << 6);
        if (tt < 62) loadK(kLoad, (tt + 2) << 6);

        if (tt < 63) qkComp(sNxt, kNext);

        float mx = sCur[0][0];
#pragma unroll
        for (int jt = 0; jt < 4; ++jt)
#pragma unroll
            for (int e = 0; e < 4; ++e) mx = fmaxf(mx, sCur[jt][e]);
        if (!__all(mx <= m + 11.541561f)) {
            mx = fmaxf(mx, __shfl_xor(mx, 16));
            mx = fmaxf(mx, __shfl_xor(mx, 32));
            float mnew = fmaxf(m, mx);
            float sc = exp2_fast(m - mnew);
            l *= sc;
#pragma unroll
            for (int ct = 0; ct < 16; ++ct)
#pragma unroll
                for (int e = 0; e < 4; ++e) acc[ct][e] *= sc;
            m = mnew;
        }
        float sum = 0.f;
#pragma unroll
        for (int jt = 0; jt < 4; ++jt)
#pragma unroll
            for (int e = 0; e < 4; ++e) {
                float p = exp2_fast(sCur[jt][e] - m);
                sCur[jt][e] = p;
                sum += p;
            }
        l += sum;

        const char* vsb = (const char*)vs[buf];
#pragma unroll
        for (int h = 0; h < 2; ++h) {
            union { unsigned u[4]; bh8 v; } pf;
            pf.u[0] = packbf(sCur[2 * h + 0][0], sCur[2 * h + 0][1]);
            pf.u[1] = packbf(sCur[2 * h + 0][2], sCur[2 * h + 0][3]);
            pf.u[2] = packbf(sCur[2 * h + 1][0], sCur[2 * h + 1][1]);
            pf.u[3] = packbf(sCur[2 * h + 1][2], sCur[2 * h + 1][3]);
            bh8 pb = pf.v;
            __builtin_amdgcn_s_setprio(1);
#pragma unroll
            for (int ct = 0; ct < 16; ++ct) {
                int c = 16 * ct + li;
                int off = c * 128 + ((64 * h + 16 * g) ^ ((c & 7) << 4));
                bh8 vf = *(const bh8*)(vsb + off);
                acc[ct] = __builtin_amdgcn_mfma_f32_16x16x32_bf16(vf, pb, acc[ct], 0, 0, 0);
            }
            __builtin_amdgcn_s_setprio(0);
        }
        __syncthreads();
    };

    for (int tt = 0; tt < 64; tt += 2) {
        step(tt, kf1, kf0, sA, sB, 0);
        step(tt + 1, kf0, kf1, sB, sA, 1);
    }

    l += __shfl_xor(l, 16);
    l += __shfl_xor(l, 32);

    float gm = gamma[0];
    float rl = 1.f / l;
    const float* xb = x + ((size_t)b * CC) * NN;
    float* ob = out + ((size_t)b * CC) * NN;
    int i = qb + li;
#pragma unroll
    for (int ct = 0; ct < 16; ++ct)
#pragma unroll
        for (int e = 0; e < 4; ++e) {
            int c = 16 * ct + 4 * g + e;
            size_t idx = (size_t)c * NN + i;
            ob[idx] = gm * (acc[ct][e] * rl) + xb[idx];
        }
}

// ---------------------------------------------------------------------------
extern "C" void kernel_launch(void* const* d_in, const int* in_sizes, int n_in,
                              void* d_out, int out_size, void* d_ws, size_t ws_size,
                              hipStream_t stream) {
    const float* x = (const float*)d_in[0];
    const float* Wq = (const float*)d_in[1];
    const float* bq = (const float*)d_in[2];
    const float* Wk = (const float*)d_in[3];
    const float* bk = (const float*)d_in[4];
    const float* Wv = (const float*)d_in[5];
    const float* bv = (const float*)d_in[6];
    const float* gamma = (const float*)d_in[7];
    float* out = (float*)d_out;

    // workspace layout (bytes):
    // q64 @0 (4MB) | k64 @4MB | vC @8MB (16MB) | Whi @24MB (160KB) |
    // Wlo @24MB+160KB | bcat @24MB+320KB
    unsigned short* ws16 = (unsigned short*)d_ws;
    unsigned short* q64w = ws16;
    unsigned short* k64w = ws16 + 2097152;
    unsigned short* vCw = ws16 + 4194304;
    unsigned short* Whiw = ws16 + 12582912;
    unsigned short* Wlow = Whiw + 81920;
    float* bcatw = (float*)(Wlow + 81920);

    prep_w_kernel<<<320, 256, 0, stream>>>(Wq, bq, Wk, bk, Wv, bv, Whiw, Wlow, bcatw);
    qkv_kernel<<<BB * (NN / 64), 256, 0, stream>>>(x, Whiw, Wlow, bcatw, q64w, k64w, vCw);
    attn_kernel<<<512, 256, 0, stream>>>(q64w, k64w, vCw, x, gamma, out);
}